// Round 1
// 4713.085 us; speedup vs baseline: 1.1929x; 1.1929x over previous
//
#include <hip/hip_runtime.h>

#define T_LEN 256
#define B_SZ  64
#define H_SZ  1024
#define G4H   4096
#define HB    (B_SZ * H_SZ)              // 65536
#define NBLK  256
#define NSTEP (T_LEN + 2)                // skew-2 pipeline: s = 0..257

typedef __attribute__((ext_vector_type(8))) short short8;
typedef __attribute__((ext_vector_type(4))) float float4_;
typedef __attribute__((ext_vector_type(4))) unsigned int uint4_;
typedef __attribute__((ext_vector_type(8))) unsigned int uint8_;

__device__ __forceinline__ unsigned short bf16_rne(float x) {
  unsigned u = __builtin_bit_cast(unsigned, x);
  unsigned r = u + 0x7FFFu + ((u >> 16) & 1u);
  return (unsigned short)(r >> 16);
}
__device__ __forceinline__ float bf16_to_f32(unsigned short s) {
  unsigned u = ((unsigned)s) << 16;
  return __builtin_bit_cast(float, u);
}

// ---------- prep: x fp32 -> packed split-bf16 (hi | lo<<16) dwords ----------
__global__ __launch_bounds__(256)
void pack_x(const float* __restrict__ src, unsigned* __restrict__ dst) {
  const size_t i = ((size_t)blockIdx.x * 256 + threadIdx.x) * 4;
  float4_ v = *(const float4_*)(src + i);
  uint4_ o;
  #pragma unroll
  for (int j = 0; j < 4; ++j) {
    const unsigned short h = bf16_rne(v[j]);
    const unsigned short l = bf16_rne(v[j] - bf16_to_f32(h));
    o[j] = (unsigned)h | ((unsigned)l << 16);
  }
  *(uint4_*)(dst + i) = o;
}

// ---------- prep: h0 -> ring slot 3 (t = -1) + zero barrier state ----------
__global__ __launch_bounds__(256)
void init_h(const float* __restrict__ h0, unsigned* __restrict__ ringp,
            unsigned* __restrict__ bar) {
  if (blockIdx.x == 0) {
    #pragma unroll
    for (int j = 0; j < 4; ++j) bar[threadIdx.x * 4 + j] = 0u;
  }
  const int e0 = (blockIdx.x * 256 + threadIdx.x) * 4;
  #pragma unroll
  for (int j = 0; j < 4; ++j) {
    const int e = e0 + j;                 // [2][B][H] = 131072 elems
    const int l = e >> 16;
    const int rem = e & (HB - 1);
    const float v = h0[e];
    const unsigned hh = bf16_rne(v);
    const unsigned ll = bf16_rne(v - bf16_to_f32((unsigned short)hh));
    ringp[(size_t)(l * 4 + 3) * HB + rem] = hh | (ll << 16);
  }
}

// one input-side (or recurrent-side) half-GEMM: 96 MFMAs per wave.
// src: packed [64][1024] hi|lo dwords; wp: [plane(hi,lo)][ntile][kb] B-fragments.
__device__ __forceinline__ void accum_side(float4_ (&acc)[4][2],
                                           const unsigned* src,
                                           const short8 (&wp)[2][2][4],
                                           const int nn, const int quad,
                                           const int wave) {
  #pragma unroll
  for (int kb = 0; kb < 4; ++kb) {
    const int k0 = wave * 128 + kb * 32 + quad * 8;
    #pragma unroll
    for (int m = 0; m < 4; ++m) {
      const int row = m * 16 + nn;
      const uint8_ u = *(const uint8_*)(src + (size_t)row * H_SZ + k0);
      uint4_ h4, l4;
      #pragma unroll
      for (int r = 0; r < 4; ++r) {   // v_perm unpack: 8 inst per hi/lo pair
        h4[r] = __builtin_amdgcn_perm(u[2 * r + 1], u[2 * r], 0x05040100u);
        l4[r] = __builtin_amdgcn_perm(u[2 * r + 1], u[2 * r], 0x07060302u);
      }
      const short8 hi = __builtin_bit_cast(short8, h4);
      const short8 lo = __builtin_bit_cast(short8, l4);
      #pragma unroll
      for (int nt = 0; nt < 2; ++nt) {
        acc[m][nt] = __builtin_amdgcn_mfma_f32_16x16x32_bf16(hi, wp[0][nt][kb], acc[m][nt], 0, 0, 0);
        acc[m][nt] = __builtin_amdgcn_mfma_f32_16x16x32_bf16(lo, wp[0][nt][kb], acc[m][nt], 0, 0, 0);
        acc[m][nt] = __builtin_amdgcn_mfma_f32_16x16x32_bf16(hi, wp[1][nt][kb], acc[m][nt], 0, 0, 0);
      }
    }
  }
}

// ---------- persistent LSTM: 256 WGs x 512 thr, skew-2 layer pipeline ----------
// Step s: layer0 computes t=s, layer1 computes t=s-2. The input-side half of
// each step's GEMM is computed in the barrier SHADOW (between arrive and wait):
// layer0's x is static; layer1's x-input h0(t) is one full barrier old at skew-2.
__global__ __launch_bounds__(512, 2)
void lstm_persist(const unsigned* __restrict__ xp,     // packed x [T][B][H]
                  const float* __restrict__ c0_in,
                  const float* __restrict__ Wih,       // fp32 [L][4H][H]
                  const float* __restrict__ Whh,
                  const float* __restrict__ bih,
                  const float* __restrict__ bhh,
                  unsigned* __restrict__ ringp,        // [L][4 slots][B][H] packed
                  float* __restrict__ out,
                  unsigned* __restrict__ bar)
{
  const int wg    = blockIdx.x;
  const int layer = wg >> 7;
  const int cb    = wg & 127;
  const int tid   = threadIdx.x;
  const int lane  = tid & 63;
  const int wave  = tid >> 6;    // 0..7 : K-slice of 128
  const int nn    = lane & 15;
  const int quad  = lane >> 4;

  // [wave][batch][gate-permuted col], stride 36: reduce reads are aligned
  // b128 at bank-spread addresses; writes are 2-way (free).
  __shared__ float lds[8][64][36];

  int growA[2];
  #pragma unroll
  for (int nt = 0; nt < 2; ++nt) {
    const int q = nt * 2 + (nn >> 3);
    growA[nt] = q * H_SZ + cb * 8 + (nn & 7);
  }

  // ---- one-time: fp32 weights -> split-bf16 register fragments (no prep kernel)
  short8 wreg[2][2][2][4];  // [mat(ih,hh)][plane(hi,lo)][ntile][kb]
  #pragma unroll
  for (int mat = 0; mat < 2; ++mat) {
    const float* wsrc = mat ? Whh : Wih;
    #pragma unroll
    for (int nt = 0; nt < 2; ++nt)
      #pragma unroll
      for (int kb = 0; kb < 4; ++kb) {
        const float* p = wsrc + ((size_t)layer * G4H + growA[nt]) * H_SZ +
                         wave * 128 + kb * 32 + quad * 8;
        short8 hi, lo;
        #pragma unroll
        for (int j = 0; j < 8; ++j) {
          const float v = p[j];
          const unsigned short h = bf16_rne(v);
          hi[j] = (short)h;
          lo[j] = (short)bf16_rne(v - bf16_to_f32(h));
        }
        wreg[mat][0][nt][kb] = hi;
        wreg[mat][1][nt][kb] = lo;
      }
  }

  // ---- reduce-phase thread mapping + bias preload (no presum kernel)
  const int rb    = tid >> 3;
  const int rhc   = tid & 7;
  const int rhcol = cb * 8 + rhc;
  float4_ bias4;
  #pragma unroll
  for (int q = 0; q < 4; ++q)
    bias4[q] = bih[layer * G4H + q * H_SZ + rhcol] +
               bhh[layer * G4H + q * H_SZ + rhcol];

  unsigned* grp = bar + 32 * (1 + (wg >> 5));
  unsigned* go  = bar + 32 * (9 + (wg >> 5));

  float creg = 0.f;
  float4_ acc[4][2];
  #pragma unroll
  for (int m = 0; m < 4; ++m)
    #pragma unroll
    for (int nt = 0; nt < 2; ++nt)
      acc[m][nt] = float4_{0.f, 0.f, 0.f, 0.f};

  // prologue: layer0's x-side for t=0 (layer1's first x-side runs in shadow of s=1)
  if (layer == 0) accum_side(acc, xp, wreg[0], nn, quad, wave);

  #pragma unroll 1
  for (int s = 0; s < NSTEP; ++s) {
    const int t = (layer == 0) ? s : s - 2;
    if (t >= 0 && t < T_LEN) {
      // ---- post-release critical path: recurrent half only ----
      const unsigned* hq = ringp + (size_t)(layer * 4 + ((t - 1) & 3)) * HB;
      accum_side(acc, hq, wreg[1], nn, quad, wave);

      // partials -> LDS, gate-permuted col = hcol*4 + gate
      #pragma unroll
      for (int m = 0; m < 4; ++m)
        #pragma unroll
        for (int nt = 0; nt < 2; ++nt)
          #pragma unroll
          for (int r = 0; r < 4; ++r)
            lds[wave][m * 16 + quad * 4 + r]
               [((nn & 7) << 2) + nt * 2 + (nn >> 3)] = acc[m][nt][r];
      __syncthreads();

      // reduce over 8 K-waves: 8 aligned ds_read_b128 + fused elementwise
      float4_ g4 = bias4;
      #pragma unroll
      for (int w = 0; w < 8; ++w)
        g4 += *(const float4_*)&lds[w][rb][rhc << 2];
      const float cprev = (t == 0)
          ? c0_in[(size_t)layer * HB + (size_t)rb * H_SZ + rhcol]
          : creg;
      const float ig = 1.f / (1.f + __expf(-g4[0]));
      const float fg = 1.f / (1.f + __expf(-g4[1]));
      const float gg = tanhf(g4[2]);
      const float og = 1.f / (1.f + __expf(-g4[3]));
      const float cn = fg * cprev + ig * gg;
      const float hn = og * tanhf(cn);
      creg = cn;
      const size_t ridx = (size_t)(layer * 4 + (t & 3)) * HB +
                          (size_t)rb * H_SZ + rhcol;
      const unsigned hh = bf16_rne(hn);
      const unsigned ll = bf16_rne(hn - bf16_to_f32((unsigned short)hh));
      __hip_atomic_store(&ringp[ridx], hh | (ll << 16),
                         __ATOMIC_RELAXED, __HIP_MEMORY_SCOPE_AGENT);
      if (layer == 1 && t == T_LEN - 1)
        out[(size_t)rb * H_SZ + rhcol] = hn;
    }
    if (s == NSTEP - 1) break;

    // ---- barrier ARRIVE (thread0 non-blocking) ----
    __syncthreads();   // compiler drains vmcnt: ring stores at coherence point
    unsigned led = 0;
    if (tid == 0) {
      __builtin_amdgcn_s_waitcnt(0);
      const unsigned a = __hip_atomic_fetch_add(grp, 1u, __ATOMIC_RELAXED,
                                                __HIP_MEMORY_SCOPE_AGENT);
      if ((a & 31u) == 31u) {
        __hip_atomic_fetch_add(bar, 1u, __ATOMIC_RELAXED,
                               __HIP_MEMORY_SCOPE_AGENT);
        led = 1u;
      }
    }

    // ---- SHADOW: next step's input-side half-GEMM (barrier-independent) ----
    // layer0: x_{s+1} (static). layer1: h0(s-1), released at barrier s-1.
    const int tn = (layer == 0) ? s + 1 : s - 1;
    if (tn >= 0 && tn < T_LEN) {
      #pragma unroll
      for (int m = 0; m < 4; ++m)
        #pragma unroll
        for (int nt = 0; nt < 2; ++nt)
          acc[m][nt] = float4_{0.f, 0.f, 0.f, 0.f};
      const unsigned* xq = (layer == 0) ? (xp + (size_t)tn * HB)
                                        : (ringp + (size_t)(tn & 3) * HB);
      accum_side(acc, xq, wreg[0], nn, quad, wave);
    }

    // ---- barrier WAIT + acquire ----
    if (tid == 0) {
      const unsigned t1 = (unsigned)s + 1u;
      if (led) {
        while (__hip_atomic_load(bar, __ATOMIC_RELAXED,
                                 __HIP_MEMORY_SCOPE_AGENT) < 8u * t1)
          __builtin_amdgcn_s_sleep(2);
        __hip_atomic_store(go, t1, __ATOMIC_RELAXED, __HIP_MEMORY_SCOPE_AGENT);
      } else {
        while (__hip_atomic_load(go, __ATOMIC_RELAXED,
                                 __HIP_MEMORY_SCOPE_AGENT) < t1)
          __builtin_amdgcn_s_sleep(2);
      }
      __builtin_amdgcn_fence(__ATOMIC_ACQUIRE, "agent");  // fresh ring reads
    }
    __syncthreads();
  }
}

extern "C" void kernel_launch(void* const* d_in, const int* in_sizes, int n_in,
                              void* d_out, int out_size, void* d_ws, size_t ws_size,
                              hipStream_t stream) {
  (void)in_sizes; (void)n_in; (void)out_size; (void)ws_size;
  const float* x   = (const float*)d_in[0];
  const float* h0  = (const float*)d_in[1];
  const float* c0  = (const float*)d_in[2];
  const float* Wih = (const float*)d_in[3];
  const float* Whh = (const float*)d_in[4];
  const float* bih = (const float*)d_in[5];
  const float* bhh = (const float*)d_in[6];
  float* out = (float*)d_out;

  // workspace (~69.2 MB): xpack 64 MB | ring 2 MB | bar 4 KB
  char* w = (char*)d_ws;
  unsigned* xpack = (unsigned*)w;                                   // T*HB uints
  unsigned* ringp = (unsigned*)(w + (size_t)T_LEN * HB * 4);        // 2L*4slots*HB
  unsigned* bar   = (unsigned*)(w + (size_t)T_LEN * HB * 4
                                  + (size_t)8 * HB * 4);            // 4 KB

  pack_x<<<(T_LEN * HB) / 4 / 256, 256, 0, stream>>>(x, xpack);
  init_h<<<2 * HB / 4 / 256, 256, 0, stream>>>(h0, ringp, bar);
  lstm_persist<<<NBLK, 512, 0, stream>>>(xpack, c0, Wih, Whh, bih, bhh,
                                         ringp, out, bar);
}